// Round 6
// baseline (245.669 us; speedup 1.0000x reference)
//
#include <hip/hip_runtime.h>
#include <hip/hip_bf16.h>
#include <hip/hip_cooperative_groups.h>

namespace cg = cooperative_groups;

#define HW 16384
#define NB 4

typedef __attribute__((ext_vector_type(8))) short bf16x8;
typedef __attribute__((ext_vector_type(4))) float f32x4;

__device__ __forceinline__ float blo(unsigned u) { return __uint_as_float(u << 16); }
__device__ __forceinline__ float bhi(unsigned u) { return __uint_as_float(u & 0xffff0000u); }

// ws byte layout:
// [0,16384)      Wbf16 [2][64 d][64 c] ushort (0=keys, 1=queries)
// [16384,16896)  combined bias f32 [128]
// [32768,+4.2MB) keys bf16 [4][16384][64]

#define DOT2(s_, idxn_) do {                                                  \
    const char* kp = kb_ + ((size_t)(idxn_) * 128);                           \
    uint2 k0 = *(const uint2*)(kp);                                           \
    uint2 k1 = *(const uint2*)(kp + 32);                                      \
    uint2 k2 = *(const uint2*)(kp + 64);                                      \
    uint2 k3 = *(const uint2*)(kp + 96);                                      \
    float a0, a1;                                                             \
    a0 = blo(k0.x) * qt0[0];           a1 = bhi(k0.x) * qt0[1];               \
    a0 = fmaf(blo(k0.y), qt0[2], a0);  a1 = fmaf(bhi(k0.y), qt0[3], a1);      \
    a0 = fmaf(blo(k1.x), qt1[0], a0);  a1 = fmaf(bhi(k1.x), qt1[1], a1);      \
    a0 = fmaf(blo(k1.y), qt1[2], a0);  a1 = fmaf(bhi(k1.y), qt1[3], a1);      \
    a0 = fmaf(blo(k2.x), qt2[0], a0);  a1 = fmaf(bhi(k2.x), qt2[1], a1);      \
    a0 = fmaf(blo(k2.y), qt2[2], a0);  a1 = fmaf(bhi(k2.y), qt2[3], a1);      \
    a0 = fmaf(blo(k3.x), qt3[0], a0);  a1 = fmaf(bhi(k3.x), qt3[1], a1);      \
    a0 = fmaf(blo(k3.y), qt3[2], a0);  a1 = fmaf(bhi(k3.y), qt3[3], a1);      \
    float a = a0 + a1;                                                        \
    a += __shfl_xor(a, 16);                                                   \
    a += __shfl_xor(a, 32);                                                   \
    if (kg == 0) res[(w * 16 + ncol) * 26 + (s_)] = a * 0.125f;               \
} while (0)

#define SAMP2(s_, dy_, dx_) do {                                              \
    int ry = y + (dy_);                                                       \
    if ((dy_) < 0) ry = (ry < 0) ? -ry : ry;                                  \
    if ((dy_) > 0) ry = (ry > 127) ? 254 - ry : ry;                           \
    int rx = xq + (dx_);                                                      \
    if ((dx_) < 0) rx = (rx < 0) ? -rx : rx;                                  \
    if ((dx_) > 0) rx = (rx > 127) ? 254 - rx : rx;                           \
    DOT2(s_, (ry << 7) + rx);                                                 \
} while (0)

// Single cooperative kernel. 512 blocks x 256 threads (2 blocks/CU needed;
// launch_bounds(256,2) -> <=256 VGPR, LDS 16.6KB -> residency has big margin).
// Phase 0 (blocks 0..31): fold linear layers -> Wb bf16, bias f32.
// Phase 1: 2 tiles/block of 64 nodes: MFMA -> keys global bf16, queries regs.
// Phase 2: 26 gather-dots per node.
__global__ __launch_bounds__(256, 2) void fused_all(
    const float* __restrict__ x,
    const float* __restrict__ conv_w, const float* __restrict__ conv_b,
    const float* __restrict__ key_w, const float* __restrict__ key_b,
    const float* __restrict__ query_w, const float* __restrict__ query_b,
    ushort* __restrict__ Wb, float* __restrict__ biasp,
    ushort* __restrict__ keys, const int* __restrict__ rnd,
    float* __restrict__ out) {
    __shared__ ushort xs[64 * 64];    // 8 KB
    __shared__ ushort epi[64 * 64];   // 8 KB; res[] in phase 2
    __shared__ float bs[128];
    int t = threadIdx.x, bx = blockIdx.x;

    // ---- phase 0 ----
    if (bx < 32) {
        int sel = bx >> 4, d0 = (bx & 15) * 4;
        const float* Wm = sel ? query_w : key_w;
        int dd = t >> 6, c = t & 63;
        const float* wrow = Wm + (d0 + dd) * 64;   // wave-uniform
        float acc = 0.f;
        #pragma unroll
        for (int k = 0; k < 64; ++k) acc = fmaf(wrow[k], conv_w[k * 64 + c], acc);
        __hip_bfloat16 h = __float2bfloat16(acc);
        Wb[(sel * 64 + d0 + dd) * 64 + c] = *(ushort*)&h;
        if (t < 4) {
            const float* wr2 = Wm + (d0 + t) * 64;
            float bacc = 0.f;
            #pragma unroll
            for (int k = 0; k < 64; ++k) bacc = fmaf(wr2[k], conv_b[k], bacc);
            bacc += (sel ? query_b : key_b)[d0 + t];
            biasp[sel * 64 + d0 + t] = bacc;
        }
    }
    __threadfence();
    cg::this_grid().sync();

    // ---- phase 1 ----
    if (t < 128) bs[t] = biasp[t];
    int l = t & 63, w = t >> 6;
    int ncol = l & 15, kg = l >> 4;

    f32x4 q[2][4];
    #pragma unroll
    for (int ti = 0; ti < 2; ++ti) {
        int tile = bx + ti * 512;
        int b = tile >> 8;
        int n0 = (tile & 255) << 6;

        {   // stage x: thread -> node t&63, channel quarter t>>6, cvt bf16
            int r = t & 63, q0 = t >> 6;
            const float* xp = x + ((size_t)(b * 64 + q0 * 16)) * HW + n0 + r;
            unsigned u[8];
            #pragma unroll
            for (int cc = 0; cc < 8; ++cc) {
                float lo = xp[(size_t)(2 * cc) * HW];
                float hi = xp[(size_t)(2 * cc + 1) * HW];
                __hip_bfloat162 h2 = __float22bfloat162_rn(make_float2(lo, hi));
                u[cc] = *(unsigned*)&h2;
            }
            #pragma unroll
            for (int qq = 0; qq < 2; ++qq) {
                int c16 = q0 * 2 + qq;
                *(uint4*)((char*)xs + r * 128 + ((c16 ^ (r & 7)) << 4)) =
                    make_uint4(u[4 * qq], u[4 * qq + 1], u[4 * qq + 2], u[4 * qq + 3]);
            }
        }
        __syncthreads();

        bf16x8 Bf[2];
        int brow = w * 16 + ncol;
        #pragma unroll
        for (int half = 0; half < 2; ++half)
            Bf[half] = *(bf16x8*)((char*)xs + brow * 128 + (((half * 4 + kg) ^ (brow & 7)) << 4));

        f32x4 acc[8];
        #pragma unroll
        for (int dt = 0; dt < 8; ++dt) acc[dt] = (f32x4){0.f, 0.f, 0.f, 0.f};
        #pragma unroll
        for (int dt = 0; dt < 8; ++dt) {
            const bf16x8* arow = (const bf16x8*)(Wb + (dt * 16 + ncol) * 64 + kg * 8);
            acc[dt] = __builtin_amdgcn_mfma_f32_16x16x32_bf16(arow[0], Bf[0], acc[dt], 0, 0, 0);
            acc[dt] = __builtin_amdgcn_mfma_f32_16x16x32_bf16(arow[4], Bf[1], acc[dt], 0, 0, 0);
        }

        // queries for this tile -> registers (f32, bias added)
        #pragma unroll
        for (int dt = 0; dt < 4; ++dt) {
            float4 bb = *(float4*)&bs[64 + dt * 16 + kg * 4];
            q[ti][dt] = acc[4 + dt] + (f32x4){bb.x, bb.y, bb.z, bb.w};
        }

        // keys epilogue: swizzled LDS -> coalesced global bf16
        #pragma unroll
        for (int dt = 0; dt < 4; ++dt) {
            int dbase = dt * 16 + kg * 4;
            float4 bb = *(float4*)&bs[dbase];
            int nl = w * 16 + ncol;
            f32x4 a = acc[dt];
            __hip_bfloat162 lo2 = __float22bfloat162_rn(make_float2(a[0] + bb.x, a[1] + bb.y));
            __hip_bfloat162 hi2 = __float22bfloat162_rn(make_float2(a[2] + bb.z, a[3] + bb.w));
            *(uint2*)((char*)epi + nl * 128 + (((dbase >> 3) ^ (nl & 7)) << 4) + ((dbase & 4) << 1)) =
                make_uint2(*(unsigned*)&lo2, *(unsigned*)&hi2);
        }
        __syncthreads();
        #pragma unroll
        for (int i = 0; i < 2; ++i) {
            int idx = i * 256 + t;
            int row = idx >> 3, ch = idx & 7;
            uint4 v = *(uint4*)((char*)epi + row * 128 + ((ch ^ (row & 7)) << 4));
            *(uint4*)(keys + (((size_t)(b * HW + n0 + row)) << 6) + ch * 8) = v;
        }
        __syncthreads();
    }
    __threadfence();
    cg::this_grid().sync();

    // ---- phase 2 ----
    float* res = (float*)epi;
    #pragma unroll
    for (int ti = 0; ti < 2; ++ti) {
        int tile = bx + ti * 512;
        int b = tile >> 8;
        int n0 = (tile & 255) << 6;
        int n = n0 + w * 16 + ncol;
        int y = n >> 7, xq = n & 127;
        const char* kb_ = (const char*)(keys + (((size_t)b * HW) << 6)) + kg * 8;
        int rix = rnd[b * HW + n];
        f32x4 qt0 = q[ti][0], qt1 = q[ti][1], qt2 = q[ti][2], qt3 = q[ti][3];

        SAMP2(0, -2, -2);  SAMP2(1, -2, -1);  SAMP2(2, -2, 0);   SAMP2(3, -2, 1);
        SAMP2(4, -2, 2);   SAMP2(5, -1, -2);  SAMP2(6, -1, -1);  SAMP2(7, -1, 0);
        SAMP2(8, -1, 1);   SAMP2(9, -1, 2);   SAMP2(10, 0, -2);  SAMP2(11, 0, -1);
        SAMP2(12, 0, 0);   SAMP2(13, 0, 1);   SAMP2(14, 0, 2);   SAMP2(15, 1, -2);
        SAMP2(16, 1, -1);  SAMP2(17, 1, 0);   SAMP2(18, 1, 1);   SAMP2(19, 1, 2);
        SAMP2(20, 2, -2);  SAMP2(21, 2, -1);  SAMP2(22, 2, 0);   SAMP2(23, 2, 1);
        SAMP2(24, 2, 2);   DOT2(25, rix);

        __syncthreads();
        size_t ob = ((size_t)(b * HW + n0)) * 26;
        #pragma unroll
        for (int i = 0; i < 7; ++i) {
            int idx = i * 256 + t;
            if (idx < 1664) out[ob + idx] = res[idx];
        }
        __syncthreads();
    }
}

extern "C" void kernel_launch(void* const* d_in, const int* in_sizes, int n_in,
                              void* d_out, int out_size, void* d_ws, size_t ws_size,
                              hipStream_t stream) {
    const float* x       = (const float*)d_in[0];
    const float* conv_w  = (const float*)d_in[1];
    const float* conv_b  = (const float*)d_in[2];
    const float* key_w   = (const float*)d_in[3];
    const float* key_b   = (const float*)d_in[4];
    const float* query_w = (const float*)d_in[5];
    const float* query_b = (const float*)d_in[6];
    const int*   rnd     = (const int*)d_in[7];
    float* out = (float*)d_out;

    ushort* Wb    = (ushort*)d_ws;
    float*  biasp = (float*)((char*)d_ws + 16384);
    ushort* keys  = (ushort*)((char*)d_ws + 32768);

    void* args[] = {(void*)&x, (void*)&conv_w, (void*)&conv_b,
                    (void*)&key_w, (void*)&key_b, (void*)&query_w,
                    (void*)&query_b, (void*)&Wb, (void*)&biasp,
                    (void*)&keys, (void*)&rnd, (void*)&out};
    hipLaunchCooperativeKernel((const void*)fused_all, dim3(512), dim3(256),
                               args, 0, stream);
}

// Round 7
// 42.198 us; speedup vs baseline: 5.8218x; 5.8218x over previous
//
#include <hip/hip_runtime.h>
#include <hip/hip_bf16.h>

#define HW 16384
#define NB 4

typedef __attribute__((ext_vector_type(8))) short bf16x8;
typedef __attribute__((ext_vector_type(4))) float f32x4;

__device__ __forceinline__ float blo(unsigned u) { return __uint_as_float(u << 16); }
__device__ __forceinline__ float bhi(unsigned u) { return __uint_as_float(u & 0xffff0000u); }

// ws byte layout:
// [0,16384)      Wbf16 [2][64 d][64 c] ushort (0=keys, 1=queries)
// [16384,16896)  combined bias f32 [128]
// [32768,+4.2MB) keys bf16 [4][16384][64]

// ---------------- Kernel A: fold linear layers (LDS-free) ----------------
__global__ __launch_bounds__(256) void combine_weights(
    const float* __restrict__ conv_w, const float* __restrict__ conv_b,
    const float* __restrict__ key_w, const float* __restrict__ key_b,
    const float* __restrict__ query_w, const float* __restrict__ query_b,
    ushort* __restrict__ Wb, float* __restrict__ bout) {
    int t = threadIdx.x, bx = blockIdx.x;
    int sel = bx >> 4, d0 = (bx & 15) * 4;
    const float* Wm = sel ? query_w : key_w;
    int dd = t >> 6, c = t & 63;
    const float* wrow = Wm + (d0 + dd) * 64;   // wave-uniform
    float acc = 0.f;
    #pragma unroll
    for (int k = 0; k < 64; ++k) acc = fmaf(wrow[k], conv_w[k * 64 + c], acc);
    __hip_bfloat16 h = __float2bfloat16(acc);
    Wb[(sel * 64 + d0 + dd) * 64 + c] = *(ushort*)&h;
    if (t < 4) {
        const float* wr2 = Wm + (d0 + t) * 64;
        float bacc = 0.f;
        #pragma unroll
        for (int k = 0; k < 64; ++k) bacc = fmaf(wr2[k], conv_b[k], bacc);
        bacc += (sel ? query_b : key_b)[d0 + t];
        bout[sel * 64 + d0 + t] = bacc;
    }
}

// ---- shared staging helper: x tile (64 nodes x 64 ch) -> swizzled bf16 LDS ----
__device__ __forceinline__ void stage_x(const float* __restrict__ x, ushort* xs,
                                        int b, int n0, int t) {
    int r = t & 63, q0 = t >> 6;
    const float* xp = x + ((size_t)(b * 64 + q0 * 16)) * HW + n0 + r;
    unsigned u[8];
    #pragma unroll
    for (int cc = 0; cc < 8; ++cc) {
        float lo = xp[(size_t)(2 * cc) * HW];
        float hi = xp[(size_t)(2 * cc + 1) * HW];
        __hip_bfloat162 h2 = __float22bfloat162_rn(make_float2(lo, hi));
        u[cc] = *(unsigned*)&h2;
    }
    #pragma unroll
    for (int qq = 0; qq < 2; ++qq) {
        int c16 = q0 * 2 + qq;
        *(uint4*)((char*)xs + r * 128 + ((c16 ^ (r & 7)) << 4)) =
            make_uint4(u[4 * qq], u[4 * qq + 1], u[4 * qq + 2], u[4 * qq + 3]);
    }
}

// ---------------- Kernel B: keys-only MFMA GEMM, 64-node tiles ----------------
__global__ __launch_bounds__(256) void gemm_keys(
    const float* __restrict__ x, const ushort* __restrict__ W,
    const float* __restrict__ bias, ushort* __restrict__ keys) {
    __shared__ ushort xs[64 * 64];
    __shared__ ushort epi[64 * 64];
    __shared__ float bs[64];
    int t = threadIdx.x;
    int b = blockIdx.x >> 8;
    int n0 = (blockIdx.x & 255) << 6;

    if (t < 64) bs[t] = bias[t];
    stage_x(x, xs, b, n0, t);
    __syncthreads();

    int l = t & 63, w = t >> 6;
    int ncol = l & 15, kg = l >> 4;

    bf16x8 Bf[2];
    int brow = w * 16 + ncol;
    #pragma unroll
    for (int half = 0; half < 2; ++half)
        Bf[half] = *(bf16x8*)((char*)xs + brow * 128 + (((half * 4 + kg) ^ (brow & 7)) << 4));

    f32x4 acc[4];
    #pragma unroll
    for (int dt = 0; dt < 4; ++dt) acc[dt] = (f32x4){0.f, 0.f, 0.f, 0.f};
    #pragma unroll
    for (int dt = 0; dt < 4; ++dt) {
        const bf16x8* arow = (const bf16x8*)(W + (dt * 16 + ncol) * 64 + kg * 8);
        acc[dt] = __builtin_amdgcn_mfma_f32_16x16x32_bf16(arow[0], Bf[0], acc[dt], 0, 0, 0);
        acc[dt] = __builtin_amdgcn_mfma_f32_16x16x32_bf16(arow[4], Bf[1], acc[dt], 0, 0, 0);
    }

    #pragma unroll
    for (int dt = 0; dt < 4; ++dt) {
        int dbase = dt * 16 + kg * 4;
        float4 bb = *(float4*)&bs[dbase];
        int nl = w * 16 + ncol;
        f32x4 a = acc[dt];
        __hip_bfloat162 lo2 = __float22bfloat162_rn(make_float2(a[0] + bb.x, a[1] + bb.y));
        __hip_bfloat162 hi2 = __float22bfloat162_rn(make_float2(a[2] + bb.z, a[3] + bb.w));
        *(uint2*)((char*)epi + nl * 128 + (((dbase >> 3) ^ (nl & 7)) << 4) + ((dbase & 4) << 1)) =
            make_uint2(*(unsigned*)&lo2, *(unsigned*)&hi2);
    }
    __syncthreads();
    #pragma unroll
    for (int i = 0; i < 2; ++i) {
        int idx = i * 256 + t;
        int row = idx >> 3, ch = idx & 7;
        uint4 v = *(uint4*)((char*)epi + row * 128 + ((ch ^ (row & 7)) << 4));
        *(uint4*)(keys + (((size_t)(b * HW + n0 + row)) << 6) + ch * 8) = v;
    }
}

// ---------------- Kernel C: queries in-register + gather + dot ----------------
#define DOT(s_, idxn_) do {                                                   \
    const uint4* kp = (const uint4*)(kb_ + ((size_t)(idxn_) << 6));           \
    uint4 ka = kp[0], kc = kp[1];                                             \
    float a = 0.f;                                                            \
    a = fmaf(blo(ka.x), qf[0], a);  a = fmaf(bhi(ka.x), qf[1], a);            \
    a = fmaf(blo(ka.y), qf[2], a);  a = fmaf(bhi(ka.y), qf[3], a);            \
    a = fmaf(blo(ka.z), qf[4], a);  a = fmaf(bhi(ka.z), qf[5], a);            \
    a = fmaf(blo(ka.w), qf[6], a);  a = fmaf(bhi(ka.w), qf[7], a);            \
    a = fmaf(blo(kc.x), qf[8], a);  a = fmaf(bhi(kc.x), qf[9], a);            \
    a = fmaf(blo(kc.y), qf[10], a); a = fmaf(bhi(kc.y), qf[11], a);           \
    a = fmaf(blo(kc.z), qf[12], a); a = fmaf(bhi(kc.z), qf[13], a);           \
    a = fmaf(blo(kc.w), qf[14], a); a = fmaf(bhi(kc.w), qf[15], a);           \
    a += __shfl_xor(a, 1);                                                    \
    a += __shfl_xor(a, 2);                                                    \
    if (j == 0) res[n_loc * 26 + (s_)] = a * 0.125f;                          \
} while (0)

#define SAMP(s_, dy_, dx_) do {                                               \
    int ry = y + (dy_);                                                       \
    if ((dy_) < 0) ry = (ry < 0) ? -ry : ry;                                  \
    if ((dy_) > 0) ry = (ry > 127) ? 254 - ry : ry;                           \
    int rx = xq + (dx_);                                                      \
    if ((dx_) < 0) rx = (rx < 0) ? -rx : rx;                                  \
    if ((dx_) > 0) rx = (rx > 127) ? 254 - rx : rx;                           \
    DOT(s_, (ry << 7) + rx);                                                  \
} while (0)

__global__ __launch_bounds__(256) void query_affinity(
    const float* __restrict__ x, const ushort* __restrict__ W,
    const float* __restrict__ bias, const ushort* __restrict__ keys,
    const int* __restrict__ rnd, float* __restrict__ out) {
    __shared__ ushort xs[64 * 64];   // x staging; reused as res[] (6656 B)
    __shared__ ushort qs[64 * 64];   // queries bf16, swizzled
    __shared__ float bs[64];
    int t = threadIdx.x;
    int b = blockIdx.x >> 8;
    int n0 = (blockIdx.x & 255) << 6;

    if (t < 64) bs[t] = bias[64 + t];
    stage_x(x, xs, b, n0, t);
    __syncthreads();

    int l = t & 63, w = t >> 6;
    int ncol = l & 15, kg = l >> 4;

    bf16x8 Bf[2];
    int brow = w * 16 + ncol;
    #pragma unroll
    for (int half = 0; half < 2; ++half)
        Bf[half] = *(bf16x8*)((char*)xs + brow * 128 + (((half * 4 + kg) ^ (brow & 7)) << 4));

    f32x4 acc[4];
    #pragma unroll
    for (int dt = 0; dt < 4; ++dt) acc[dt] = (f32x4){0.f, 0.f, 0.f, 0.f};
    #pragma unroll
    for (int dt = 0; dt < 4; ++dt) {
        const bf16x8* arow = (const bf16x8*)(W + (64 + dt * 16 + ncol) * 64 + kg * 8);
        acc[dt] = __builtin_amdgcn_mfma_f32_16x16x32_bf16(arow[0], Bf[0], acc[dt], 0, 0, 0);
        acc[dt] = __builtin_amdgcn_mfma_f32_16x16x32_bf16(arow[4], Bf[1], acc[dt], 0, 0, 0);
    }

    // queries -> swizzled LDS (bf16, bias added)
    #pragma unroll
    for (int dt = 0; dt < 4; ++dt) {
        int dbase = dt * 16 + kg * 4;
        float4 bb = *(float4*)&bs[dbase];
        int nl = w * 16 + ncol;
        f32x4 a = acc[dt];
        __hip_bfloat162 lo2 = __float22bfloat162_rn(make_float2(a[0] + bb.x, a[1] + bb.y));
        __hip_bfloat162 hi2 = __float22bfloat162_rn(make_float2(a[2] + bb.z, a[3] + bb.w));
        *(uint2*)((char*)qs + nl * 128 + (((dbase >> 3) ^ (nl & 7)) << 4) + ((dbase & 4) << 1)) =
            make_uint2(*(unsigned*)&lo2, *(unsigned*)&hi2);
    }
    __syncthreads();   // qs ready; xs now dead -> reuse as res

    float* res = (float*)xs;
    int j = t & 3;
    int n_loc = t >> 2;      // 64 nodes, 4 lanes each
    uint4 qa = *(uint4*)((char*)qs + n_loc * 128 + (((2 * j) ^ (n_loc & 7)) << 4));
    uint4 qb = *(uint4*)((char*)qs + n_loc * 128 + (((2 * j + 1) ^ (n_loc & 7)) << 4));
    float qf[16];
    qf[0] = blo(qa.x); qf[1] = bhi(qa.x); qf[2] = blo(qa.y); qf[3] = bhi(qa.y);
    qf[4] = blo(qa.z); qf[5] = bhi(qa.z); qf[6] = blo(qa.w); qf[7] = bhi(qa.w);
    qf[8] = blo(qb.x); qf[9] = bhi(qb.x); qf[10] = blo(qb.y); qf[11] = bhi(qb.y);
    qf[12] = blo(qb.z); qf[13] = bhi(qb.z); qf[14] = blo(qb.w); qf[15] = bhi(qb.w);

    int n = n0 + n_loc;
    int y = n >> 7, xq = n & 127;
    const ushort* kb_ = keys + (((size_t)b * HW) << 6) + j * 16;
    int rix = rnd[b * HW + n];

    SAMP(0, -2, -2);  SAMP(1, -2, -1);  SAMP(2, -2, 0);   SAMP(3, -2, 1);
    SAMP(4, -2, 2);   SAMP(5, -1, -2);  SAMP(6, -1, -1);  SAMP(7, -1, 0);
    SAMP(8, -1, 1);   SAMP(9, -1, 2);   SAMP(10, 0, -2);  SAMP(11, 0, -1);
    SAMP(12, 0, 0);   SAMP(13, 0, 1);   SAMP(14, 0, 2);   SAMP(15, 1, -2);
    SAMP(16, 1, -1);  SAMP(17, 1, 0);   SAMP(18, 1, 1);   SAMP(19, 1, 2);
    SAMP(20, 2, -2);  SAMP(21, 2, -1);  SAMP(22, 2, 0);   SAMP(23, 2, 1);
    SAMP(24, 2, 2);   DOT(25, rix);

    __syncthreads();
    size_t ob = ((size_t)(b * HW + n0)) * 26;
    #pragma unroll
    for (int i = 0; i < 7; ++i) {
        int idx = i * 256 + t;
        if (idx < 1664) out[ob + idx] = res[idx];
    }
}

extern "C" void kernel_launch(void* const* d_in, const int* in_sizes, int n_in,
                              void* d_out, int out_size, void* d_ws, size_t ws_size,
                              hipStream_t stream) {
    const float* x       = (const float*)d_in[0];
    const float* conv_w  = (const float*)d_in[1];
    const float* conv_b  = (const float*)d_in[2];
    const float* key_w   = (const float*)d_in[3];
    const float* key_b   = (const float*)d_in[4];
    const float* query_w = (const float*)d_in[5];
    const float* query_b = (const float*)d_in[6];
    const int*   rnd     = (const int*)d_in[7];
    float* out = (float*)d_out;

    ushort* Wb    = (ushort*)d_ws;
    float*  biasp = (float*)((char*)d_ws + 16384);
    ushort* keys  = (ushort*)((char*)d_ws + 32768);

    combine_weights<<<32, 256, 0, stream>>>(conv_w, conv_b, key_w, key_b,
                                            query_w, query_b, Wb, biasp);
    gemm_keys<<<NB * (HW / 64), 256, 0, stream>>>(x, Wb, biasp, keys);
    query_affinity<<<NB * (HW / 64), 256, 0, stream>>>(x, Wb, biasp, keys, rnd, out);
}

// Round 8
// 34.416 us; speedup vs baseline: 7.1382x; 1.2261x over previous
//
#include <hip/hip_runtime.h>
#include <hip/hip_bf16.h>

#define HW 16384
#define NB 4

typedef __attribute__((ext_vector_type(8))) short bf16x8;
typedef __attribute__((ext_vector_type(4))) float f32x4;

__device__ __forceinline__ float blo(unsigned u) { return __uint_as_float(u << 16); }
__device__ __forceinline__ float bhi(unsigned u) { return __uint_as_float(u & 0xffff0000u); }

// ws byte layout:
// [0,16384)      Wbf16 [2][64 d][64 c] ushort (0=keys, 1=queries*0.125)
// [16384,16896)  combined bias f32 [128] (query half pre-scaled by 0.125)
// [32768,+4.2MB) keys    bf16 [4][16384][64]
// [+4.2MB,+4.2MB) queries bf16 [4][16384][64] (pre-scaled by 0.125)

// ---------------- Kernel A: fold linear layers (LDS-free) ----------------
__global__ __launch_bounds__(256) void combine_weights(
    const float* __restrict__ conv_w, const float* __restrict__ conv_b,
    const float* __restrict__ key_w, const float* __restrict__ key_b,
    const float* __restrict__ query_w, const float* __restrict__ query_b,
    ushort* __restrict__ Wb, float* __restrict__ bout) {
    int t = threadIdx.x, bx = blockIdx.x;
    int sel = bx >> 4, d0 = (bx & 15) * 4;
    const float* Wm = sel ? query_w : key_w;
    float scale = sel ? 0.125f : 1.0f;      // fold C^-0.5 into the query side (exact)
    int dd = t >> 6, c = t & 63;
    const float* wrow = Wm + (d0 + dd) * 64;   // wave-uniform
    float acc = 0.f;
    #pragma unroll
    for (int k = 0; k < 64; ++k) acc = fmaf(wrow[k], conv_w[k * 64 + c], acc);
    __hip_bfloat16 h = __float2bfloat16(acc * scale);
    Wb[(sel * 64 + d0 + dd) * 64 + c] = *(ushort*)&h;
    if (t < 4) {
        const float* wr2 = Wm + (d0 + t) * 64;
        float bacc = 0.f;
        #pragma unroll
        for (int k = 0; k < 64; ++k) bacc = fmaf(wr2[k], conv_b[k], bacc);
        bacc += (sel ? query_b : key_b)[d0 + t];
        bout[sel * 64 + d0 + t] = bacc * scale;
    }
}

// ---------------- Kernel B: MFMA GEMM, 128-node tiles, float4-along-n staging ----------------
// 512 blocks. Waves: 2n x 2d grid, each wave 64n x 64d (32 MFMA).
__global__ __launch_bounds__(256) void gemm_kq(
    const float* __restrict__ x, const ushort* __restrict__ W,
    const float* __restrict__ bias, ushort* __restrict__ keys,
    ushort* __restrict__ queries) {
    __shared__ ushort xs[128 * 64];    // 16 KB, [n][c] bf16, 16B-chunk XOR swizzle
    __shared__ ushort epi[2 * 128 * 64]; // 32 KB: [arr][n][64 d]
    __shared__ float bs[128];
    int t = threadIdx.x;
    int b = blockIdx.x >> 7;
    int n0 = (blockIdx.x & 127) << 7;

    if (t < 128) bs[t] = bias[t];
    {   // stage: thread -> c rows c0..c0+7, nodes nb..nb+3 (float4 along n)
        int c0 = (t >> 5) * 8, nb = (t & 31) * 4;
        const float* xp = x + ((size_t)(b * 64 + c0)) * HW + n0 + nb;
        float4 v[8];
        #pragma unroll
        for (int r = 0; r < 8; ++r) v[r] = *(const float4*)(xp + (size_t)r * HW);
        int chunk = c0 >> 3;
        #pragma unroll
        for (int nn = 0; nn < 4; ++nn) {
            unsigned u[4];
            #pragma unroll
            for (int cc = 0; cc < 4; ++cc) {
                float lo = ((const float*)&v[2 * cc])[nn];
                float hi = ((const float*)&v[2 * cc + 1])[nn];
                __hip_bfloat162 h2 = __float22bfloat162_rn(make_float2(lo, hi));
                u[cc] = *(unsigned*)&h2;
            }
            int row = nb + nn;
            *(uint4*)((char*)xs + row * 128 + ((chunk ^ (row & 7)) << 4)) =
                make_uint4(u[0], u[1], u[2], u[3]);
        }
    }
    __syncthreads();

    int l = t & 63, w = t >> 6;
    int ncol = l & 15, kg = l >> 4;
    int nhalf = w & 1, dhalf = w >> 1;

    bf16x8 Bf[4][2];
    #pragma unroll
    for (int nt = 0; nt < 4; ++nt) {
        int row = nhalf * 64 + nt * 16 + ncol;
        #pragma unroll
        for (int half = 0; half < 2; ++half)
            Bf[nt][half] = *(bf16x8*)((char*)xs + row * 128 + (((half * 4 + kg) ^ (row & 7)) << 4));
    }

    f32x4 acc[4][4];   // [dt][nt]
    #pragma unroll
    for (int dt = 0; dt < 4; ++dt)
        #pragma unroll
        for (int nt = 0; nt < 4; ++nt) acc[dt][nt] = (f32x4){0.f, 0.f, 0.f, 0.f};

    #pragma unroll
    for (int dt = 0; dt < 4; ++dt) {
        const bf16x8* arow = (const bf16x8*)(W + ((dhalf * 64 + dt * 16 + ncol)) * 64 + kg * 8);
        bf16x8 A0 = arow[0];
        bf16x8 A1 = arow[4];
        #pragma unroll
        for (int nt = 0; nt < 4; ++nt) {
            acc[dt][nt] = __builtin_amdgcn_mfma_f32_16x16x32_bf16(A0, Bf[nt][0], acc[dt][nt], 0, 0, 0);
            acc[dt][nt] = __builtin_amdgcn_mfma_f32_16x16x32_bf16(A1, Bf[nt][1], acc[dt][nt], 0, 0, 0);
        }
    }

    // epilogue: wave writes its 64n x 64d into epi[dhalf]
    #pragma unroll
    for (int dt = 0; dt < 4; ++dt) {
        int dbase = dt * 16 + kg * 4;
        float4 bb = *(float4*)&bs[dhalf * 64 + dbase];
        #pragma unroll
        for (int nt = 0; nt < 4; ++nt) {
            int nl = nhalf * 64 + nt * 16 + ncol;
            f32x4 a = acc[dt][nt];
            __hip_bfloat162 lo2 = __float22bfloat162_rn(make_float2(a[0] + bb.x, a[1] + bb.y));
            __hip_bfloat162 hi2 = __float22bfloat162_rn(make_float2(a[2] + bb.z, a[3] + bb.w));
            *(uint2*)((char*)epi + dhalf * 16384 + nl * 128 +
                      (((dbase >> 3) ^ (nl & 7)) << 4) + ((dbase & 4) << 1)) =
                make_uint2(*(unsigned*)&lo2, *(unsigned*)&hi2);
        }
    }
    __syncthreads();
    #pragma unroll
    for (int i = 0; i < 8; ++i) {
        int u = i * 256 + t;              // 0..2047 uint4s
        int arr = u >> 10;                // 0=keys, 1=queries
        int row = (u >> 3) & 127, ch = u & 7;
        uint4 v = *(uint4*)((char*)epi + arr * 16384 + row * 128 + ((ch ^ (row & 7)) << 4));
        ushort* dst = arr ? queries : keys;
        *(uint4*)(dst + (((size_t)(b * HW + n0 + row)) << 6) + ch * 8) = v;
    }
}

// ---------------- Kernel C: gather + dot (R4-proven), scale pre-folded ----------------
#define DOT(s_, idxn_) do {                                                   \
    const uint4* kp = (const uint4*)(kb_ + ((size_t)(idxn_) << 6));           \
    uint4 ka = kp[0], kc = kp[1];                                             \
    float a = 0.f;                                                            \
    a = fmaf(blo(ka.x), qf[0], a);  a = fmaf(bhi(ka.x), qf[1], a);            \
    a = fmaf(blo(ka.y), qf[2], a);  a = fmaf(bhi(ka.y), qf[3], a);            \
    a = fmaf(blo(ka.z), qf[4], a);  a = fmaf(bhi(ka.z), qf[5], a);            \
    a = fmaf(blo(ka.w), qf[6], a);  a = fmaf(bhi(ka.w), qf[7], a);            \
    a = fmaf(blo(kc.x), qf[8], a);  a = fmaf(bhi(kc.x), qf[9], a);            \
    a = fmaf(blo(kc.y), qf[10], a); a = fmaf(bhi(kc.y), qf[11], a);           \
    a = fmaf(blo(kc.z), qf[12], a); a = fmaf(bhi(kc.z), qf[13], a);           \
    a = fmaf(blo(kc.w), qf[14], a); a = fmaf(bhi(kc.w), qf[15], a);           \
    a += __shfl_xor(a, 1);                                                    \
    a += __shfl_xor(a, 2);                                                    \
    if (j == 0) res[n_loc * 26 + (s_)] = a;                                   \
} while (0)

#define SAMP(s_, dy_, dx_) do {                                               \
    int ry = y + (dy_);                                                       \
    if ((dy_) < 0) ry = (ry < 0) ? -ry : ry;                                  \
    if ((dy_) > 0) ry = (ry > 127) ? 254 - ry : ry;                           \
    int rx = xq + (dx_);                                                      \
    if ((dx_) < 0) rx = (rx < 0) ? -rx : rx;                                  \
    if ((dx_) > 0) rx = (rx > 127) ? 254 - rx : rx;                           \
    DOT(s_, (ry << 7) + rx);                                                  \
} while (0)

__global__ __launch_bounds__(256) void affinity(
    const ushort* __restrict__ keys, const ushort* __restrict__ queries,
    const int* __restrict__ rnd, float* __restrict__ out) {
    __shared__ float res[416];
    int t = threadIdx.x;
    int b = blockIdx.x >> 10;
    int n0 = (blockIdx.x & 1023) << 4;

    int j = t & 3;
    int g = t >> 2;
    int n_loc = g & 15;
    int sb = g >> 4;          // wave-uniform sample phase
    int n = n0 + n_loc;

    const uint4* qp = (const uint4*)(queries + (((size_t)(b * HW + n)) << 6) + j * 16);
    uint4 qa = qp[0], qb = qp[1];
    float qf[16];
    qf[0] = blo(qa.x); qf[1] = bhi(qa.x); qf[2] = blo(qa.y); qf[3] = bhi(qa.y);
    qf[4] = blo(qa.z); qf[5] = bhi(qa.z); qf[6] = blo(qa.w); qf[7] = bhi(qa.w);
    qf[8] = blo(qb.x); qf[9] = bhi(qb.x); qf[10] = blo(qb.y); qf[11] = bhi(qb.y);
    qf[12] = blo(qb.z); qf[13] = bhi(qb.z); qf[14] = blo(qb.w); qf[15] = bhi(qb.w);

    int y = n >> 7, xq = n & 127;
    const ushort* kb_ = keys + (((size_t)b * HW) << 6) + j * 16;

    switch (sb) {
    case 0:
        SAMP(0, -2, -2); SAMP(4, -2, 2);  SAMP(8, -1, 1);  SAMP(12, 0, 0);
        SAMP(16, 1, -1); SAMP(20, 2, -2); SAMP(24, 2, 2);
        break;
    case 1: {
        SAMP(1, -2, -1); SAMP(5, -1, -2); SAMP(9, -1, 2);  SAMP(13, 0, 1);
        SAMP(17, 1, 0);  SAMP(21, 2, -1);
        int rix = rnd[b * HW + n];
        DOT(25, rix);
        break;
    }
    case 2:
        SAMP(2, -2, 0);  SAMP(6, -1, -1); SAMP(10, 0, -2); SAMP(14, 0, 2);
        SAMP(18, 1, 1);  SAMP(22, 2, 0);
        break;
    default:
        SAMP(3, -2, 1);  SAMP(7, -1, 0);  SAMP(11, 0, -1); SAMP(15, 1, -2);
        SAMP(19, 1, 2);  SAMP(23, 2, 1);
        break;
    }
    __syncthreads();
    size_t ob = ((size_t)(b * HW + n0)) * 26;
    out[ob + t] = res[t];
    if (t < 160) out[ob + 256 + t] = res[256 + t];
}

extern "C" void kernel_launch(void* const* d_in, const int* in_sizes, int n_in,
                              void* d_out, int out_size, void* d_ws, size_t ws_size,
                              hipStream_t stream) {
    const float* x       = (const float*)d_in[0];
    const float* conv_w  = (const float*)d_in[1];
    const float* conv_b  = (const float*)d_in[2];
    const float* key_w   = (const float*)d_in[3];
    const float* key_b   = (const float*)d_in[4];
    const float* query_w = (const float*)d_in[5];
    const float* query_b = (const float*)d_in[6];
    const int*   rnd     = (const int*)d_in[7];
    float* out = (float*)d_out;

    ushort* Wb    = (ushort*)d_ws;
    float*  biasp = (float*)((char*)d_ws + 16384);
    ushort* keys  = (ushort*)((char*)d_ws + 32768);
    ushort* quer  = keys + (size_t)NB * HW * 64;

    combine_weights<<<32, 256, 0, stream>>>(conv_w, conv_b, key_w, key_b,
                                            query_w, query_b, Wb, biasp);
    gemm_kq<<<NB * (HW / 128), 256, 0, stream>>>(x, Wb, biasp, keys, quer);
    affinity<<<NB * (HW / 16), 256, 0, stream>>>(keys, quer, rnd, out);
}